// Round 5
// baseline (1006.841 us; speedup 1.0000x reference)
//
#include <hip/hip_runtime.h>
#include <hip/hip_bf16.h>
#include <cmath>

#define NB 4
#define NNEG 33
#define NN 10000
#define NE 100000
#define NW 3
#define DD 64
#define NL 3
#define NR 200
#define NFL 2
#define NFFN 256
#define LN_EPS 1e-5f
#define RPB 4   // rows per k_xform block (132 = 33*4)

// ---- ws layout (float offsets) ----
// Interleaved state layout: XI[n][b][d] (node-major) so one dwordx4/lane
// covers all 4 batches of one node row.
#define OFF_QUERY 0                                   // NB*DD
#define OFF_H0    256                                 // NB ints
#define OFF_TSW   288                                 // NB*NNEG ints
#define OFF_MINT  448                                 // 1 int
#define OFF_RELI  512                                 // NL*NR*NB*DD  relI[l][et][b][d]
#define OFF_TWI   (OFF_RELI + NL*NR*NB*DD)            // NL*NR*NB*DD  (b-replicated tw)
#define OFF_TBI   (OFF_TWI + NL*NR*NB*DD)             // NL*NR*NB*DD  (b-replicated tb)
#define OFF_X     (OFF_TBI + NL*NR*NB*DD)             // NN*NB*DD (interleaved)
#define OFF_AGG   (OFF_X + NB*NN*DD)                  // NN*NB*DD (interleaved)
#define OFF_TOK   (OFF_AGG + NB*NN*DD)                // NB*NNEG*NW*DD
#define OFF_X2    (OFF_TOK + NB*NNEG*NW*DD)           // NN*NB*DD (interleaved)
// int offsets (4B units)
#define IOFF_PTR  (OFF_X2 + NB*NN*DD)                 // NW*(NN+1) ints
#define IOFF_CUR  (IOFF_PTR + NW*(NN+1))              // NW*NN ints
#define IOFF_REC  ((IOFF_CUR + NW*NN + 3) & ~3)       // NW*NE*4 ints, 16B aligned

// ---------------- prep ----------------
__global__ void k_prep(const int* __restrict__ qt, const float* __restrict__ qemb,
                       float* __restrict__ ws) {
  int tid = threadIdx.x;
  if (tid < NB * DD) {
    int b = tid / DD, d = tid % DD;
    int h0 = qt[(b * NNEG + 0) * 3 + 0];
    bool itn = true;
    for (int j = 1; j < NNEG; ++j) itn = itn && (qt[(b * NNEG + j) * 3 + 0] == h0);
    int r0 = qt[(b * NNEG + 0) * 3 + 1] + (itn ? 0 : NR / 2);
    ws[OFF_QUERY + b * DD + d] = qemb[r0 * DD + d];
    if (d == 0) {
      int t0 = qt[(b * NNEG + 0) * 3 + 2];
      ((int*)ws)[OFF_H0 + b] = itn ? h0 : t0;
    }
  }
  if (tid < NB * NNEG) {
    int b = tid / NNEG, j = tid % NNEG;
    int h0 = qt[(b * NNEG + 0) * 3 + 0];
    bool itn = true;
    for (int jj = 1; jj < NNEG; ++jj) itn = itn && (qt[(b * NNEG + jj) * 3 + 0] == h0);
    int h = qt[(b * NNEG + j) * 3 + 0], t = qt[(b * NNEG + j) * 3 + 2];
    ((int*)ws)[OFF_TSW + tid] = itn ? t : h;
  }
  if (tid == 0) ((int*)ws)[OFF_MINT] = 0x7fffffff;
}

// ---------------- min over edge_time[0] ----------------
__global__ void k_mint(const int* __restrict__ etime, float* __restrict__ ws) {
  int i = blockIdx.x * blockDim.x + threadIdx.x;
  int v = (i < NE) ? etime[i] : 0x7fffffff;
  for (int m = 1; m < 64; m <<= 1) v = min(v, __shfl_xor(v, m));
  if ((threadIdx.x & 63) == 0) atomicMin(&((int*)ws)[OFF_MINT], v);
}

// ---------------- zero ptr array ----------------
__global__ void k_zero_ptr(float* __restrict__ ws) {
  int i = blockIdx.x * 256 + threadIdx.x;
  if (i < NW * (NN + 1)) ((int*)ws)[IOFF_PTR + i] = 0;
}

// ---------------- b-replicated tw/tb tables ----------------
__global__ void k_twprep(const float* __restrict__ tw, const float* __restrict__ tb,
                         float* __restrict__ ws) {
  int idx = blockIdx.x * 256 + threadIdx.x;
  if (idx >= NL * NR * NB * DD) return;
  int l = idx / (NR * NB * DD);
  int rem = idx % (NR * NB * DD);
  int et = rem >> 8;       // NB*DD = 256
  int d = rem & 63;
  float wv = tw[(l * NR + et) * DD + d];
  float bv = tb[(l * NR + et) * DD + d];
  ws[OFF_TWI + idx] = wv;
  ws[OFF_TBI + idx] = bv;
}

// ---------------- histogram of dst ----------------
__global__ void k_hist(const int* __restrict__ eidx, float* __restrict__ ws) {
  int e = blockIdx.x * 256 + threadIdx.x, w = blockIdx.y;
  if (e >= NE) return;
  int dst = eidx[(w * 2 + 1) * NE + e];
  atomicAdd(&((int*)ws)[IOFF_PTR + w * (NN + 1) + dst + 1], 1);
}

// ---------------- inclusive scan -> ptr (one block per w) ----------------
__global__ void k_scan(float* __restrict__ ws) {
  int w = blockIdx.x;
  int* p = (int*)ws + IOFF_PTR + w * (NN + 1);
  __shared__ int wsum[4];
  __shared__ int runv;
  if (threadIdx.x == 0) runv = 0;
  __syncthreads();
  int lane = threadIdx.x & 63, wv = threadIdx.x >> 6;
  for (int base = 0; base < NN + 1; base += 256) {
    int i = base + threadIdx.x;
    int v = (i <= NN) ? p[i] : 0;
    for (int off = 1; off < 64; off <<= 1) {
      int t = __shfl_up(v, off);
      if (lane >= off) v += t;
    }
    if (lane == 63) wsum[wv] = v;
    __syncthreads();
    int add = runv;
    for (int u = 0; u < wv; ++u) add += wsum[u];
    v += add;
    if (i <= NN) p[i] = v;
    __syncthreads();
    if (threadIdx.x == 255) runv = v;
    __syncthreads();
  }
}

// ---------------- cursor init ----------------
__global__ void k_curinit(float* __restrict__ ws) {
  int i = blockIdx.x * 256 + threadIdx.x;
  if (i >= NW * NN) return;
  int w = i / NN, n = i % NN;
  ((int*)ws)[IOFF_CUR + i] = ((int*)ws)[IOFF_PTR + w * (NN + 1) + n];
}

// ---------------- scatter edges into CSR records {src, et, dt, weight} ----------------
__global__ void k_scatter(const int* __restrict__ eidx, const int* __restrict__ etype,
                          const int* __restrict__ etime, const float* __restrict__ eweight,
                          float* __restrict__ ws) {
  int e = blockIdx.x * 256 + threadIdx.x, w = blockIdx.y;
  if (e >= NE) return;
  int* wsi = (int*)ws;
  int dst = eidx[(w * 2 + 1) * NE + e];
  int pos = atomicAdd(&wsi[IOFF_CUR + w * NN + dst], 1);
  float dt = (float)etime[w * NE + e] - (float)wsi[OFF_MINT];
  int4 rec;
  rec.x = eidx[(w * 2 + 0) * NE + e];
  rec.y = etype[w * NE + e];
  rec.z = __float_as_int(dt);
  rec.w = __float_as_int(eweight[w * NE + e]);
  ((int4*)(wsi + IOFF_REC))[(size_t)w * NE + pos] = rec;
}

// ---------------- rel = query @ rel_lin_w.T + b (written interleaved) ----------------
__global__ void k_rel(const float* __restrict__ rlw, const float* __restrict__ rlb,
                      float* __restrict__ ws) {
  int l = blockIdx.y;
  int rd = blockIdx.x * blockDim.x + threadIdx.x;  // (r,d) flat, < 12800
  const float4* wrow = (const float4*)(rlw + ((size_t)(l * NR * DD + rd)) * DD);
  float4 wreg[16];
#pragma unroll
  for (int kk = 0; kk < 16; ++kk) wreg[kk] = wrow[kk];
  float bias = rlb[l * NR * DD + rd];
  int r = rd >> 6, d = rd & 63;
  for (int b = 0; b < NB; ++b) {
    const float4* q4 = (const float4*)(ws + OFF_QUERY + b * DD);
    float acc = 0.f;
#pragma unroll
    for (int kk = 0; kk < 16; ++kk) {
      float4 q = q4[kk];
      acc += q.x * wreg[kk].x + q.y * wreg[kk].y + q.z * wreg[kk].z + q.w * wreg[kk].w;
    }
    ws[OFF_RELI + (size_t)(l * NR + r) * (NB * DD) + b * DD + d] = acc + bias;
  }
}

// ---------------- CSR gather aggregation (interleaved): wave per node ----------------
// lane = b*16 + q; lane covers batch b, dims 4q..4q+3; one dwordx4 per table per edge.
__global__ __launch_bounds__(256) void k_agg(const float* __restrict__ xcur,
                                             float* __restrict__ ws, int w, int l,
                                             int init0) {
  int lane = threadIdx.x & 63;
  int wv = threadIdx.x >> 6;
  int n = blockIdx.x * 4 + wv;
  int b = lane >> 4;
  const int* wsi = (const int*)ws;
  int p0 = __builtin_amdgcn_readfirstlane(wsi[IOFF_PTR + w * (NN + 1) + n]);
  int p1 = __builtin_amdgcn_readfirstlane(wsi[IOFF_PTR + w * (NN + 1) + n + 1]);
  const int4* recs = ((const int4*)(wsi + IOFF_REC)) + (size_t)w * NE;
  const float4* XI4 = (const float4*)xcur;
  const float4* RELI4 = (const float4*)(ws + OFF_RELI) + (size_t)l * NR * 64;
  const float4* TWI4 = (const float4*)(ws + OFF_TWI) + (size_t)l * NR * 64;
  const float4* TBI4 = (const float4*)(ws + OFF_TBI) + (size_t)l * NR * 64;
  int h00 = wsi[OFF_H0 + 0], h01 = wsi[OFF_H0 + 1];
  int h02 = wsi[OFF_H0 + 2], h03 = wsi[OFF_H0 + 3];
  int h0b = wsi[OFF_H0 + b];
  float4 q4b = ((const float4*)(ws + OFF_QUERY))[lane];  // query[b][4q..4q+3]
  float4 acc;
  if (n == h0b) acc = q4b;
  else { acc.x = 0.f; acc.y = 0.f; acc.z = 0.f; acc.w = 0.f; }

  if (init0) {
    // x == init: only edges with src == some h0 contribute
    for (int j = p0; j < p1; ++j) {
      int4 rec = recs[j];
      int src = rec.x;
      if (!((src == h00) | (src == h01) | (src == h02) | (src == h03))) continue;
      int et = rec.y;
      float dtf = __int_as_float(rec.z);
      float m = (src == h0b) ? __int_as_float(rec.w) : 0.f;
      int base = et * 64 + lane;
      float4 r4 = RELI4[base];
      float4 w4 = TWI4[base];
      float4 b4 = TBI4[base];
      acc.x = fmaf(q4b.x * r4.x, cosf(fmaf(dtf, w4.x, b4.x)) * m, acc.x);
      acc.y = fmaf(q4b.y * r4.y, cosf(fmaf(dtf, w4.y, b4.y)) * m, acc.y);
      acc.z = fmaf(q4b.z * r4.z, cosf(fmaf(dtf, w4.z, b4.z)) * m, acc.z);
      acc.w = fmaf(q4b.w * r4.w, cosf(fmaf(dtf, w4.w, b4.w)) * m, acc.w);
    }
  } else {
#define EDGE_BODY(J)                                                        \
    {                                                                       \
      int4 rec = recs[J];                                                   \
      int src = rec.x, et = rec.y;                                          \
      float dtf = __int_as_float(rec.z), wgt = __int_as_float(rec.w);       \
      int base = et * 64 + lane;                                            \
      float4 x4 = XI4[(size_t)src * 64 + lane];                             \
      float4 r4 = RELI4[base];                                              \
      float4 w4 = TWI4[base];                                               \
      float4 b4 = TBI4[base];                                               \
      acc.x = fmaf(x4.x * r4.x, cosf(fmaf(dtf, w4.x, b4.x)) * wgt, acc.x);  \
      acc.y = fmaf(x4.y * r4.y, cosf(fmaf(dtf, w4.y, b4.y)) * wgt, acc.y);  \
      acc.z = fmaf(x4.z * r4.z, cosf(fmaf(dtf, w4.z, b4.z)) * wgt, acc.z);  \
      acc.w = fmaf(x4.w * r4.w, cosf(fmaf(dtf, w4.w, b4.w)) * wgt, acc.w);  \
    }
    int j = p0;
    for (; j + 1 < p1; j += 2) {
      EDGE_BODY(j);
      EDGE_BODY(j + 1);
    }
    if (j < p1) EDGE_BODY(j);
#undef EDGE_BODY
  }
  ((float4*)(ws + OFF_AGG))[(size_t)n * 64 + lane] = acc;
}

// ---------------- node GEMM + LN + residual (interleaved rows, LDS weights) --------
// rows are (n,b) pairs: row = n*4 + b. wave = 8 rows x 64 output cols.
__global__ __launch_bounds__(256) void k_gemm(const float* __restrict__ linw,
                                              const float* __restrict__ linb,
                                              const float* __restrict__ lns,
                                              const float* __restrict__ lnb,
                                              const float* __restrict__ xsrc,
                                              float* __restrict__ xdst,
                                              const float* __restrict__ ws, int l,
                                              int init0) {
  __shared__ float4 wt4[64 * 33];  // lin_w[l] as [c][128] padded to 132 floats
  {
    const float4* lw4 = (const float4*)(linw + (size_t)l * DD * 2 * DD);
    for (int idx = threadIdx.x; idx < 2048; idx += 256)
      wt4[(idx >> 5) * 33 + (idx & 31)] = lw4[idx];
  }
  __syncthreads();
  int wv = threadIdx.x >> 6;
  int c = threadIdx.x & 63;
  int row0 = blockIdx.x * 32 + wv * 8;
  const float4* XI4 = (const float4*)xsrc;
  const float4* AG4 = (const float4*)(ws + OFF_AGG);
  const int* wsi = (const int*)ws;
  int nr[8], br[8];
  size_t rowbase[8];
#pragma unroll
  for (int r = 0; r < 8; ++r) {
    nr[r] = (row0 + r) >> 2;
    br[r] = (row0 + r) & 3;
    rowbase[r] = (size_t)nr[r] * 64 + br[r] * 16;
  }
  float bias = linb[l * DD + c];
  float acc[8];
#pragma unroll
  for (int r = 0; r < 8; ++r) acc[r] = bias;
  if (init0) {
    // x == init: x-part nonzero only where n == h0[b]
#pragma unroll
    for (int r = 0; r < 8; ++r) {
      if (nr[r] == wsi[OFF_H0 + br[r]]) {
        const float4* q4 = (const float4*)(ws + OFF_QUERY + br[r] * DD);
        for (int kk = 0; kk < 16; ++kk) {
          float4 q = q4[kk];
          float4 w4 = wt4[c * 33 + kk];
          acc[r] += q.x * w4.x + q.y * w4.y + q.z * w4.z + q.w * w4.w;
        }
      }
    }
  } else {
    for (int kk = 0; kk < 16; ++kk) {
      float4 w4 = wt4[c * 33 + kk];
#pragma unroll
      for (int r = 0; r < 8; ++r) {
        float4 xv = XI4[rowbase[r] + kk];
        acc[r] = fmaf(xv.x, w4.x, acc[r]);
        acc[r] = fmaf(xv.y, w4.y, acc[r]);
        acc[r] = fmaf(xv.z, w4.z, acc[r]);
        acc[r] = fmaf(xv.w, w4.w, acc[r]);
      }
    }
  }
  for (int kk = 0; kk < 16; ++kk) {
    float4 w4 = wt4[c * 33 + 16 + kk];
#pragma unroll
    for (int r = 0; r < 8; ++r) {
      float4 xv = AG4[rowbase[r] + kk];
      acc[r] = fmaf(xv.x, w4.x, acc[r]);
      acc[r] = fmaf(xv.y, w4.y, acc[r]);
      acc[r] = fmaf(xv.z, w4.z, acc[r]);
      acc[r] = fmaf(xv.w, w4.w, acc[r]);
    }
  }
  float sc = lns[l * DD + c], bc = lnb[l * DD + c];
#pragma unroll
  for (int r = 0; r < 8; ++r) {
    float v = acc[r];
    float s = v;
    for (int m = 1; m < 64; m <<= 1) s += __shfl_xor(s, m);
    float mean = s * (1.f / 64.f);
    float cv = v - mean;
    float vv = cv * cv;
    for (int m = 1; m < 64; m <<= 1) vv += __shfl_xor(vv, m);
    vv *= (1.f / 64.f);
    float y = cv * __frsqrt_rn(vv + LN_EPS) * sc + bc;
    y = fmaxf(y, 0.f);
    float xo;
    if (init0)
      xo = (nr[r] == wsi[OFF_H0 + br[r]]) ? ws[OFF_QUERY + br[r] * DD + c] : 0.f;
    else
      xo = xsrc[(size_t)nr[r] * (NB * DD) + br[r] * DD + c];
    xdst[(size_t)nr[r] * (NB * DD) + br[r] * DD + c] = xo + y;
  }
}

// ---------------- gather tail features into tokens (+pe) ----------------
__global__ void k_gather(const float* __restrict__ pe, const float* __restrict__ xfin,
                         float* __restrict__ ws, int w) {
  int i = blockIdx.x * 256 + threadIdx.x;
  if (i >= NB * NNEG * DD) return;
  int bj = i / DD, d = i % DD;
  int b = bj / NNEG;
  int t = ((const int*)ws)[OFF_TSW + bj];
  ws[OFF_TOK + bj * NW * DD + w * DD + d] =
      xfin[(size_t)t * (NB * DD) + b * DD + d] + pe[w * DD + d];
}

// ---------------- transformer + final MLP: LDS-staged weights, 4 rows/block ----------------
__global__ __launch_bounds__(768) void k_xform(
    const float* __restrict__ wq, const float* __restrict__ wk,
    const float* __restrict__ wv, const float* __restrict__ wo,
    const float* __restrict__ ffw1, const float* __restrict__ ffb1,
    const float* __restrict__ ffw2, const float* __restrict__ ffb2,
    const float* __restrict__ fln1s, const float* __restrict__ fln1b,
    const float* __restrict__ fln2s, const float* __restrict__ fln2b,
    const float* __restrict__ m1w, const float* __restrict__ m1b,
    const float* __restrict__ m2w, const float* __restrict__ m2b,
    float* __restrict__ ws, float* __restrict__ out) {
  __shared__ float tok[RPB][NW][DD], kvb[RPB][NW][DD], vvb[RPB][NW][DD];
  __shared__ float hbuf[RPB][NW][NFFN];
  __shared__ float feat[RPB][2 * DD];
  __shared__ float red[RPB][2];
  __shared__ float4 wbuf4[4352];  // 68 KB staging buffer (padded rows, 16B aligned)
  int tid = threadIdx.x;
  int rr = tid / 192;
  int t192 = tid - rr * 192;
  int tk = t192 >> 6, d = t192 & 63;
  int row = blockIdx.x * RPB + rr, b = row / NNEG;
  tok[rr][tk][d] = ws[OFF_TOK + row * NW * DD + tk * DD + d];
  for (int f = 0; f < NFL; ++f) {
    // ---- stage wq,wk,wv,wo as 4x [64][68] ----
    {
      const float4* s0 = (const float4*)(wq + (size_t)f * DD * DD);
      const float4* s1 = (const float4*)(wk + (size_t)f * DD * DD);
      const float4* s2 = (const float4*)(wv + (size_t)f * DD * DD);
      const float4* s3 = (const float4*)(wo + (size_t)f * DD * DD);
      for (int idx = tid; idx < 4096; idx += 768) {
        int m = idx >> 10, rem = idx & 1023;
        int rrow = rem >> 4, c4 = rem & 15;
        const float4* s = (m == 0) ? s0 : (m == 1) ? s1 : (m == 2) ? s2 : s3;
        wbuf4[(m * 64 + rrow) * 17 + c4] = s[rem];
      }
    }
    __syncthreads();
    // ---- QKV from LDS ----
    float qd = 0.f, kd = 0.f, vd = 0.f;
#pragma unroll
    for (int kk = 0; kk < 16; ++kk) {
      float4 tv = *(const float4*)&tok[rr][tk][4 * kk];
      float4 aq = wbuf4[(0 * 64 + d) * 17 + kk];
      float4 ak = wbuf4[(1 * 64 + d) * 17 + kk];
      float4 av = wbuf4[(2 * 64 + d) * 17 + kk];
      qd += tv.x * aq.x + tv.y * aq.y + tv.z * aq.z + tv.w * aq.w;
      kd += tv.x * ak.x + tv.y * ak.y + tv.z * ak.z + tv.w * ak.w;
      vd += tv.x * av.x + tv.y * av.y + tv.z * av.z + tv.w * av.w;
    }
    kvb[rr][tk][d] = kd;
    vvb[rr][tk][d] = vd;
    __syncthreads();
    // ---- attention (head = d>>4) ----
    float sc[NW];
#pragma unroll
    for (int j = 0; j < NW; ++j) {
      float p = qd * kvb[rr][j][d];
      p += __shfl_xor(p, 1);
      p += __shfl_xor(p, 2);
      p += __shfl_xor(p, 4);
      p += __shfl_xor(p, 8);
      sc[j] = p * 0.25f;  // 1/sqrt(16)
    }
    float mx = fmaxf(sc[0], fmaxf(sc[1], sc[2]));
    float e0 = expf(sc[0] - mx), e1 = expf(sc[1] - mx), e2 = expf(sc[2] - mx);
    float inv = 1.f / (e0 + e1 + e2);
    float od = (e0 * vvb[rr][0][d] + e1 * vvb[rr][1][d] + e2 * vvb[rr][2][d]) * inv;
    __syncthreads();
    kvb[rr][tk][d] = od;  // reuse as o-buffer
    // ---- o @ wo.T ----
    float ao = 0.f;
#pragma unroll
    for (int kk = 0; kk < 16; ++kk) {
      float4 ov = *(const float4*)&kvb[rr][tk][4 * kk];
      float4 w4 = wbuf4[(3 * 64 + d) * 17 + kk];
      ao += ov.x * w4.x + ov.y * w4.y + ov.z * w4.z + ov.w * w4.w;
    }
    float t1 = tok[rr][tk][d] + ao;
    // ---- LN1 ----
    float s = t1;
    for (int m = 1; m < 64; m <<= 1) s += __shfl_xor(s, m);
    float mean = s * (1.f / 64.f);
    float cv = t1 - mean;
    float v = cv * cv;
    for (int m = 1; m < 64; m <<= 1) v += __shfl_xor(v, m);
    v *= (1.f / 64.f);
    t1 = cv * __frsqrt_rn(v + LN_EPS) * fln1s[f * DD + d] + fln1b[f * DD + d];
    tok[rr][tk][d] = t1;
    __syncthreads();
    // ---- stage ffw1 [256][68] ----
    {
      const float4* s4 = (const float4*)(ffw1 + (size_t)f * NFFN * DD);
      for (int idx = tid; idx < 4096; idx += 768) {
        int rrow = idx >> 4, c4 = idx & 15;
        wbuf4[rrow * 17 + c4] = s4[idx];
      }
    }
    __syncthreads();
    // ---- FFN1 ----
    float h[4];
#pragma unroll
    for (int uu = 0; uu < 4; ++uu) h[uu] = ffb1[f * NFFN + d + 64 * uu];
#pragma unroll
    for (int kk = 0; kk < 16; ++kk) {
      float4 tv = *(const float4*)&tok[rr][tk][4 * kk];
      float4 w0 = wbuf4[(d + 0) * 17 + kk];
      float4 w1 = wbuf4[(d + 64) * 17 + kk];
      float4 w2 = wbuf4[(d + 128) * 17 + kk];
      float4 w3 = wbuf4[(d + 192) * 17 + kk];
      h[0] += tv.x * w0.x + tv.y * w0.y + tv.z * w0.z + tv.w * w0.w;
      h[1] += tv.x * w1.x + tv.y * w1.y + tv.z * w1.z + tv.w * w1.w;
      h[2] += tv.x * w2.x + tv.y * w2.y + tv.z * w2.z + tv.w * w2.w;
      h[3] += tv.x * w3.x + tv.y * w3.y + tv.z * w3.z + tv.w * w3.w;
    }
#pragma unroll
    for (int uu = 0; uu < 4; ++uu) hbuf[rr][tk][d + 64 * uu] = fmaxf(h[uu], 0.f);
    __syncthreads();
    // ---- stage ffw2 [64][260] ----
    {
      const float4* s4 = (const float4*)(ffw2 + (size_t)f * DD * NFFN);
      for (int idx = tid; idx < 4096; idx += 768) {
        int rrow = idx >> 6, c4 = idx & 63;
        wbuf4[rrow * 65 + c4] = s4[idx];
      }
    }
    __syncthreads();
    // ---- FFN2 ----
    float ff = ffb2[f * DD + d];
#pragma unroll 8
    for (int kk = 0; kk < 64; ++kk) {
      float4 hv = *(const float4*)&hbuf[rr][tk][4 * kk];
      float4 w4 = wbuf4[d * 65 + kk];
      ff += hv.x * w4.x + hv.y * w4.y + hv.z * w4.z + hv.w * w4.w;
    }
    float t2 = t1 + ff;
    // ---- LN2 ----
    s = t2;
    for (int m = 1; m < 64; m <<= 1) s += __shfl_xor(s, m);
    mean = s * (1.f / 64.f);
    cv = t2 - mean;
    v = cv * cv;
    for (int m = 1; m < 64; m <<= 1) v += __shfl_xor(v, m);
    v *= (1.f / 64.f);
    t2 = cv * __frsqrt_rn(v + LN_EPS) * fln2s[f * DD + d] + fln2b[f * DD + d];
    tok[rr][tk][d] = t2;
    __syncthreads();
  }
  // ---- final MLP ----
  if (tk == 2) {
    feat[rr][d] = tok[rr][2][d];
    feat[rr][DD + d] = ws[OFF_QUERY + b * DD + d];
  }
  {
    const float4* s4 = (const float4*)m1w;
    for (int idx = tid; idx < 4096; idx += 768) {
      int rrow = idx >> 5, c4 = idx & 31;
      wbuf4[rrow * 33 + c4] = s4[idx];
    }
  }
  __syncthreads();
  float partial = 0.f;
  if (t192 < 2 * DD) {
    int hh = t192;
    float acc = m1b[hh];
#pragma unroll
    for (int kk = 0; kk < 32; ++kk) {
      float4 fv = *(const float4*)&feat[rr][4 * kk];
      float4 w4 = wbuf4[hh * 33 + kk];
      acc += fv.x * w4.x + fv.y * w4.y + fv.z * w4.z + fv.w * w4.w;
    }
    acc = fmaxf(acc, 0.f);
    partial = acc * m2w[hh];
  }
  for (int m = 1; m < 64; m <<= 1) partial += __shfl_xor(partial, m);
  if (d == 0 && tk < 2) red[rr][tk] = partial;
  __syncthreads();
  if (t192 == 0) out[row] = red[rr][0] + red[rr][1] + m2b[0];
}

extern "C" void kernel_launch(void* const* d_in, const int* in_sizes, int n_in,
                              void* d_out, int out_size, void* d_ws, size_t ws_size,
                              hipStream_t stream) {
  const int* qt = (const int*)d_in[0];
  const int* eidx = (const int*)d_in[1];
  const int* etype = (const int*)d_in[2];
  const int* etime = (const int*)d_in[3];
  const float* qemb = (const float*)d_in[4];
  const float* ew = (const float*)d_in[5];
  const float* rlw = (const float*)d_in[6];
  const float* rlb = (const float*)d_in[7];
  const float* tw = (const float*)d_in[8];
  const float* tb = (const float*)d_in[9];
  const float* linw = (const float*)d_in[10];
  const float* linb = (const float*)d_in[11];
  const float* lns = (const float*)d_in[12];
  const float* lnb = (const float*)d_in[13];
  const float* pe = (const float*)d_in[14];
  const float* wq = (const float*)d_in[15];
  const float* wk = (const float*)d_in[16];
  const float* wv = (const float*)d_in[17];
  const float* wo = (const float*)d_in[18];
  const float* ffw1 = (const float*)d_in[19];
  const float* ffb1 = (const float*)d_in[20];
  const float* ffw2 = (const float*)d_in[21];
  const float* ffb2 = (const float*)d_in[22];
  const float* fln1s = (const float*)d_in[23];
  const float* fln1b = (const float*)d_in[24];
  const float* fln2s = (const float*)d_in[25];
  const float* fln2b = (const float*)d_in[26];
  const float* m1w = (const float*)d_in[27];
  const float* m1b = (const float*)d_in[28];
  const float* m2w = (const float*)d_in[29];
  const float* m2b = (const float*)d_in[30];
  float* ws = (float*)d_ws;
  float* out = (float*)d_out;

  k_prep<<<1, 256, 0, stream>>>(qt, qemb, ws);
  k_mint<<<(NE + 255) / 256, 256, 0, stream>>>(etime, ws);
  k_zero_ptr<<<(NW * (NN + 1) + 255) / 256, 256, 0, stream>>>(ws);
  k_twprep<<<(NL * NR * NB * DD + 255) / 256, 256, 0, stream>>>(tw, tb, ws);
  k_rel<<<dim3(NR * DD / 256, NL), 256, 0, stream>>>(rlw, rlb, ws);
  k_hist<<<dim3((NE + 255) / 256, NW), 256, 0, stream>>>(eidx, ws);
  k_scan<<<NW, 256, 0, stream>>>(ws);
  k_curinit<<<(NW * NN + 255) / 256, 256, 0, stream>>>(ws);
  k_scatter<<<dim3((NE + 255) / 256, NW), 256, 0, stream>>>(eidx, etype, etime, ew, ws);

  float* X = ws + OFF_X;
  float* X2 = ws + OFF_X2;
  for (int w = 0; w < NW; ++w) {
    float* cur = X;
    float* nxt = X2;
    for (int l = 0; l < NL; ++l) {
      int init0 = (l == 0) ? 1 : 0;
      k_agg<<<NN / 4, 256, 0, stream>>>(cur, ws, w, l, init0);
      k_gemm<<<NB * NN / 32, 256, 0, stream>>>(linw, linb, lns, lnb, cur, nxt, ws, l,
                                               init0);
      float* t = cur; cur = nxt; nxt = t;
    }
    k_gather<<<(NB * NNEG * DD + 255) / 256, 256, 0, stream>>>(pe, cur, ws, w);
  }
  k_xform<<<NB * NNEG / RPB, 768, 0, stream>>>(wq, wk, wv, wo, ffw1, ffb1, ffw2, ffb2,
                                                fln1s, fln1b, fln2s, fln2b, m1w, m1b, m2w,
                                                m2b, ws, out);
}

// Round 6
// 579.479 us; speedup vs baseline: 1.7375x; 1.7375x over previous
//
#include <hip/hip_runtime.h>
#include <hip/hip_bf16.h>
#include <cmath>

#define NB 4
#define NNEG 33
#define NN 10000
#define NE 100000
#define NW 3
#define DD 64
#define NL 3
#define NR 200
#define NFL 2
#define NFFN 256
#define LN_EPS 1e-5f

// ---- ws layout (float offsets) ----
// Interleaved state layout: XI[n][b][d] (node-major).
#define OFF_QUERY 0                                   // NB*DD
#define OFF_H0    256                                 // NB ints
#define OFF_TSW   288                                 // NB*NNEG ints
#define OFF_MINT  448                                 // 1 int
#define OFF_RELI  512                                 // NL*NR*NB*DD  relI[l][et][b][d]
#define OFF_TWI   (OFF_RELI + NL*NR*NB*DD)            // NL*NR*NB*DD
#define OFF_TBI   (OFF_TWI + NL*NR*NB*DD)             // NL*NR*NB*DD
#define OFF_LINT  (OFF_TBI + NL*NR*NB*DD)             // NL*2*DD*DD  linT[l][k][c]
#define OFF_X     (OFF_LINT + NL*2*DD*DD)             // NN*NB*DD (interleaved)
#define OFF_AGG   (OFF_X + NB*NN*DD)                  // NN*NB*DD
#define OFF_TOK   (OFF_AGG + NB*NN*DD)                // NB*NNEG*NW*DD
#define OFF_X2    (OFF_TOK + NB*NNEG*NW*DD)           // NN*NB*DD
// int offsets (4B units)
#define IOFF_PTR  (OFF_X2 + NB*NN*DD)                 // NW*(NN+1) ints
#define IOFF_CUR  (IOFF_PTR + NW*(NN+1))              // NW*NN ints
#define IOFF_REC  ((IOFF_CUR + NW*NN + 3) & ~3)       // NW*NE*4 ints, 16B aligned

// ---------------- prep ----------------
__global__ void k_prep(const int* __restrict__ qt, const float* __restrict__ qemb,
                       float* __restrict__ ws) {
  int tid = threadIdx.x;
  if (tid < NB * DD) {
    int b = tid / DD, d = tid % DD;
    int h0 = qt[(b * NNEG + 0) * 3 + 0];
    bool itn = true;
    for (int j = 1; j < NNEG; ++j) itn = itn && (qt[(b * NNEG + j) * 3 + 0] == h0);
    int r0 = qt[(b * NNEG + 0) * 3 + 1] + (itn ? 0 : NR / 2);
    ws[OFF_QUERY + b * DD + d] = qemb[r0 * DD + d];
    if (d == 0) {
      int t0 = qt[(b * NNEG + 0) * 3 + 2];
      ((int*)ws)[OFF_H0 + b] = itn ? h0 : t0;
    }
  }
  if (tid < NB * NNEG) {
    int b = tid / NNEG, j = tid % NNEG;
    int h0 = qt[(b * NNEG + 0) * 3 + 0];
    bool itn = true;
    for (int jj = 1; jj < NNEG; ++jj) itn = itn && (qt[(b * NNEG + jj) * 3 + 0] == h0);
    int h = qt[(b * NNEG + j) * 3 + 0], t = qt[(b * NNEG + j) * 3 + 2];
    ((int*)ws)[OFF_TSW + tid] = itn ? t : h;
  }
  if (tid == 0) ((int*)ws)[OFF_MINT] = 0x7fffffff;
}

// ---------------- min over edge_time[0] ----------------
__global__ void k_mint(const int* __restrict__ etime, float* __restrict__ ws) {
  int i = blockIdx.x * blockDim.x + threadIdx.x;
  int v = (i < NE) ? etime[i] : 0x7fffffff;
  for (int m = 1; m < 64; m <<= 1) v = min(v, __shfl_xor(v, m));
  if ((threadIdx.x & 63) == 0) atomicMin(&((int*)ws)[OFF_MINT], v);
}

// ---------------- zero ptr array ----------------
__global__ void k_zero_ptr(float* __restrict__ ws) {
  int i = blockIdx.x * 256 + threadIdx.x;
  if (i < NW * (NN + 1)) ((int*)ws)[IOFF_PTR + i] = 0;
}

// ---------------- b-replicated tw/tb tables ----------------
__global__ void k_twprep(const float* __restrict__ tw, const float* __restrict__ tb,
                         float* __restrict__ ws) {
  int idx = blockIdx.x * 256 + threadIdx.x;
  if (idx >= NL * NR * NB * DD) return;
  int l = idx / (NR * NB * DD);
  int rem = idx % (NR * NB * DD);
  int et = rem >> 8;
  int d = rem & 63;
  ws[OFF_TWI + idx] = tw[(l * NR + et) * DD + d];
  ws[OFF_TBI + idx] = tb[(l * NR + et) * DD + d];
}

// ---------------- transpose lin_w: linT[l][k][c] = lin_w[l][c][k] ----------------
__global__ void k_transpose(const float* __restrict__ lin_w, float* __restrict__ ws) {
  int idx = blockIdx.x * blockDim.x + threadIdx.x;
  if (idx < NL * 2 * DD * DD) {
    int l = idx / (2 * DD * DD), r = idx % (2 * DD * DD), k = r / DD, c = r % DD;
    ws[OFF_LINT + idx] = lin_w[(l * DD + c) * 2 * DD + k];
  }
}

// ---------------- histogram of dst ----------------
__global__ void k_hist(const int* __restrict__ eidx, float* __restrict__ ws) {
  int e = blockIdx.x * 256 + threadIdx.x, w = blockIdx.y;
  if (e >= NE) return;
  int dst = eidx[(w * 2 + 1) * NE + e];
  atomicAdd(&((int*)ws)[IOFF_PTR + w * (NN + 1) + dst + 1], 1);
}

// ---------------- inclusive scan -> ptr (one block per w) ----------------
__global__ void k_scan(float* __restrict__ ws) {
  int w = blockIdx.x;
  int* p = (int*)ws + IOFF_PTR + w * (NN + 1);
  __shared__ int wsum[4];
  __shared__ int runv;
  if (threadIdx.x == 0) runv = 0;
  __syncthreads();
  int lane = threadIdx.x & 63, wv = threadIdx.x >> 6;
  for (int base = 0; base < NN + 1; base += 256) {
    int i = base + threadIdx.x;
    int v = (i <= NN) ? p[i] : 0;
    for (int off = 1; off < 64; off <<= 1) {
      int t = __shfl_up(v, off);
      if (lane >= off) v += t;
    }
    if (lane == 63) wsum[wv] = v;
    __syncthreads();
    int add = runv;
    for (int u = 0; u < wv; ++u) add += wsum[u];
    v += add;
    if (i <= NN) p[i] = v;
    __syncthreads();
    if (threadIdx.x == 255) runv = v;
    __syncthreads();
  }
}

// ---------------- cursor init ----------------
__global__ void k_curinit(float* __restrict__ ws) {
  int i = blockIdx.x * 256 + threadIdx.x;
  if (i >= NW * NN) return;
  int w = i / NN, n = i % NN;
  ((int*)ws)[IOFF_CUR + i] = ((int*)ws)[IOFF_PTR + w * (NN + 1) + n];
}

// ---------------- scatter edges into CSR records {src, et, dt, weight} ----------------
__global__ void k_scatter(const int* __restrict__ eidx, const int* __restrict__ etype,
                          const int* __restrict__ etime, const float* __restrict__ eweight,
                          float* __restrict__ ws) {
  int e = blockIdx.x * 256 + threadIdx.x, w = blockIdx.y;
  if (e >= NE) return;
  int* wsi = (int*)ws;
  int dst = eidx[(w * 2 + 1) * NE + e];
  int pos = atomicAdd(&wsi[IOFF_CUR + w * NN + dst], 1);
  float dt = (float)etime[w * NE + e] - (float)wsi[OFF_MINT];
  int4 rec;
  rec.x = eidx[(w * 2 + 0) * NE + e];
  rec.y = etype[w * NE + e];
  rec.z = __float_as_int(dt);
  rec.w = __float_as_int(eweight[w * NE + e]);
  ((int4*)(wsi + IOFF_REC))[(size_t)w * NE + pos] = rec;
}

// ---------------- rel = query @ rel_lin_w.T + b (written interleaved) ----------------
__global__ void k_rel(const float* __restrict__ rlw, const float* __restrict__ rlb,
                      float* __restrict__ ws) {
  int l = blockIdx.y;
  int rd = blockIdx.x * blockDim.x + threadIdx.x;
  const float4* wrow = (const float4*)(rlw + ((size_t)(l * NR * DD + rd)) * DD);
  float4 wreg[16];
#pragma unroll
  for (int kk = 0; kk < 16; ++kk) wreg[kk] = wrow[kk];
  float bias = rlb[l * NR * DD + rd];
  int r = rd >> 6, d = rd & 63;
  for (int b = 0; b < NB; ++b) {
    const float4* q4 = (const float4*)(ws + OFF_QUERY + b * DD);
    float acc = 0.f;
#pragma unroll
    for (int kk = 0; kk < 16; ++kk) {
      float4 q = q4[kk];
      acc += q.x * wreg[kk].x + q.y * wreg[kk].y + q.z * wreg[kk].z + q.w * wreg[kk].w;
    }
    ws[OFF_RELI + (size_t)(l * NR + r) * (NB * DD) + b * DD + d] = acc + bias;
  }
}

// ---------------- CSR gather aggregation (interleaved): wave per node ----------------
__global__ __launch_bounds__(256) void k_agg(const float* __restrict__ xcur,
                                             float* __restrict__ ws, int w, int l,
                                             int init0) {
  int lane = threadIdx.x & 63;
  int wv = threadIdx.x >> 6;
  int n = blockIdx.x * 4 + wv;
  int b = lane >> 4;
  const int* wsi = (const int*)ws;
  int p0 = __builtin_amdgcn_readfirstlane(wsi[IOFF_PTR + w * (NN + 1) + n]);
  int p1 = __builtin_amdgcn_readfirstlane(wsi[IOFF_PTR + w * (NN + 1) + n + 1]);
  const int4* recs = ((const int4*)(wsi + IOFF_REC)) + (size_t)w * NE;
  const float4* XI4 = (const float4*)xcur;
  const float4* RELI4 = (const float4*)(ws + OFF_RELI) + (size_t)l * NR * 64;
  const float4* TWI4 = (const float4*)(ws + OFF_TWI) + (size_t)l * NR * 64;
  const float4* TBI4 = (const float4*)(ws + OFF_TBI) + (size_t)l * NR * 64;
  int h00 = wsi[OFF_H0 + 0], h01 = wsi[OFF_H0 + 1];
  int h02 = wsi[OFF_H0 + 2], h03 = wsi[OFF_H0 + 3];
  int h0b = wsi[OFF_H0 + b];
  float4 q4b = ((const float4*)(ws + OFF_QUERY))[lane];
  float4 acc;
  if (n == h0b) acc = q4b;
  else { acc.x = 0.f; acc.y = 0.f; acc.z = 0.f; acc.w = 0.f; }

  if (init0) {
    for (int j = p0; j < p1; ++j) {
      int4 rec = recs[j];
      int src = rec.x;
      if (!((src == h00) | (src == h01) | (src == h02) | (src == h03))) continue;
      int et = rec.y;
      float dtf = __int_as_float(rec.z);
      float m = (src == h0b) ? __int_as_float(rec.w) : 0.f;
      int base = et * 64 + lane;
      float4 r4 = RELI4[base];
      float4 w4 = TWI4[base];
      float4 b4 = TBI4[base];
      acc.x = fmaf(q4b.x * r4.x, cosf(fmaf(dtf, w4.x, b4.x)) * m, acc.x);
      acc.y = fmaf(q4b.y * r4.y, cosf(fmaf(dtf, w4.y, b4.y)) * m, acc.y);
      acc.z = fmaf(q4b.z * r4.z, cosf(fmaf(dtf, w4.z, b4.z)) * m, acc.z);
      acc.w = fmaf(q4b.w * r4.w, cosf(fmaf(dtf, w4.w, b4.w)) * m, acc.w);
    }
  } else {
#define EDGE_BODY(J)                                                        \
    {                                                                       \
      int4 rec = recs[J];                                                   \
      int src = rec.x, et = rec.y;                                          \
      float dtf = __int_as_float(rec.z), wgt = __int_as_float(rec.w);       \
      int base = et * 64 + lane;                                            \
      float4 x4 = XI4[(size_t)src * 64 + lane];                             \
      float4 r4 = RELI4[base];                                              \
      float4 w4 = TWI4[base];                                               \
      float4 b4 = TBI4[base];                                               \
      acc.x = fmaf(x4.x * r4.x, cosf(fmaf(dtf, w4.x, b4.x)) * wgt, acc.x);  \
      acc.y = fmaf(x4.y * r4.y, cosf(fmaf(dtf, w4.y, b4.y)) * wgt, acc.y);  \
      acc.z = fmaf(x4.z * r4.z, cosf(fmaf(dtf, w4.z, b4.z)) * wgt, acc.z);  \
      acc.w = fmaf(x4.w * r4.w, cosf(fmaf(dtf, w4.w, b4.w)) * wgt, acc.w);  \
    }
    int j = p0;
    for (; j + 1 < p1; j += 2) {
      EDGE_BODY(j);
      EDGE_BODY(j + 1);
    }
    if (j < p1) EDGE_BODY(j);
#undef EDGE_BODY
  }
  ((float4*)(ws + OFF_AGG))[(size_t)n * 64 + lane] = acc;
}

// ---------------- node GEMM + LN + residual (round-4 structure, interleaved rows) ----
// row = n*4 + b; wave = 8 rows x 64 output cols; transposed weights from global (L1).
__global__ __launch_bounds__(256) void k_gemm(const float* __restrict__ linb,
                                              const float* __restrict__ lns,
                                              const float* __restrict__ lnb,
                                              const float* __restrict__ xsrc,
                                              float* __restrict__ xdst,
                                              const float* __restrict__ ws, int l,
                                              int init0) {
  int wv = __builtin_amdgcn_readfirstlane(threadIdx.x >> 6);
  int c = threadIdx.x & 63;
  int row0 = blockIdx.x * 32 + wv * 8;
  const float* WT = ws + OFF_LINT + l * 2 * DD * DD;  // [128][64]
  const float* aggsrc = ws + OFF_AGG;
  const int* wsi = (const int*)ws;
  float bias = linb[l * DD + c];
  float acc[8];
#pragma unroll
  for (int r = 0; r < 8; ++r) acc[r] = bias;
  if (init0) {
#pragma unroll
    for (int r = 0; r < 8; ++r) {
      int nr = (row0 + r) >> 2, br = (row0 + r) & 3;
      if (nr == wsi[OFF_H0 + br]) {
        const float4* q4 = (const float4*)(ws + OFF_QUERY + br * DD);
        for (int kk = 0; kk < 16; ++kk) {
          float4 q = q4[kk];
          acc[r] = fmaf(q.x, WT[(4 * kk + 0) * DD + c], acc[r]);
          acc[r] = fmaf(q.y, WT[(4 * kk + 1) * DD + c], acc[r]);
          acc[r] = fmaf(q.z, WT[(4 * kk + 2) * DD + c], acc[r]);
          acc[r] = fmaf(q.w, WT[(4 * kk + 3) * DD + c], acc[r]);
        }
      }
    }
  } else {
    for (int kk = 0; kk < 16; ++kk) {
      float w0 = WT[(4 * kk + 0) * DD + c];
      float w1 = WT[(4 * kk + 1) * DD + c];
      float w2 = WT[(4 * kk + 2) * DD + c];
      float w3 = WT[(4 * kk + 3) * DD + c];
#pragma unroll
      for (int r = 0; r < 8; ++r) {
        float4 xv = *(const float4*)(xsrc + (size_t)(row0 + r) * DD + 4 * kk);
        acc[r] = fmaf(xv.x, w0, acc[r]);
        acc[r] = fmaf(xv.y, w1, acc[r]);
        acc[r] = fmaf(xv.z, w2, acc[r]);
        acc[r] = fmaf(xv.w, w3, acc[r]);
      }
    }
  }
  for (int kk = 0; kk < 16; ++kk) {
    float w0 = WT[(64 + 4 * kk + 0) * DD + c];
    float w1 = WT[(64 + 4 * kk + 1) * DD + c];
    float w2 = WT[(64 + 4 * kk + 2) * DD + c];
    float w3 = WT[(64 + 4 * kk + 3) * DD + c];
#pragma unroll
    for (int r = 0; r < 8; ++r) {
      float4 xv = *(const float4*)(aggsrc + (size_t)(row0 + r) * DD + 4 * kk);
      acc[r] = fmaf(xv.x, w0, acc[r]);
      acc[r] = fmaf(xv.y, w1, acc[r]);
      acc[r] = fmaf(xv.z, w2, acc[r]);
      acc[r] = fmaf(xv.w, w3, acc[r]);
    }
  }
  float sc = lns[l * DD + c], bc = lnb[l * DD + c];
#pragma unroll
  for (int r = 0; r < 8; ++r) {
    float v = acc[r];
    float s = v;
    for (int m = 1; m < 64; m <<= 1) s += __shfl_xor(s, m);
    float mean = s * (1.f / 64.f);
    float cv = v - mean;
    float vv = cv * cv;
    for (int m = 1; m < 64; m <<= 1) vv += __shfl_xor(vv, m);
    vv *= (1.f / 64.f);
    float y = cv * __frsqrt_rn(vv + LN_EPS) * sc + bc;
    y = fmaxf(y, 0.f);
    float xo;
    if (init0) {
      int nr = (row0 + r) >> 2, br = (row0 + r) & 3;
      xo = (nr == wsi[OFF_H0 + br]) ? ws[OFF_QUERY + br * DD + c] : 0.f;
    } else {
      xo = xsrc[(size_t)(row0 + r) * DD + c];
    }
    xdst[(size_t)(row0 + r) * DD + c] = xo + y;
  }
}

// ---------------- gather tail features into tokens (+pe) ----------------
__global__ void k_gather(const float* __restrict__ pe, const float* __restrict__ xfin,
                         float* __restrict__ ws, int w) {
  int i = blockIdx.x * 256 + threadIdx.x;
  if (i >= NB * NNEG * DD) return;
  int bj = i / DD, d = i % DD;
  int b = bj / NNEG;
  int t = ((const int*)ws)[OFF_TSW + bj];
  ws[OFF_TOK + bj * NW * DD + w * DD + d] =
      xfin[(size_t)t * (NB * DD) + b * DD + d] + pe[w * DD + d];
}

// ---------------- transformer + final MLP: LDS-staged weights, 1 row/block ----------------
__global__ __launch_bounds__(192) void k_xform(
    const float* __restrict__ wq, const float* __restrict__ wk,
    const float* __restrict__ wv, const float* __restrict__ wo,
    const float* __restrict__ ffw1, const float* __restrict__ ffb1,
    const float* __restrict__ ffw2, const float* __restrict__ ffb2,
    const float* __restrict__ fln1s, const float* __restrict__ fln1b,
    const float* __restrict__ fln2s, const float* __restrict__ fln2b,
    const float* __restrict__ m1w, const float* __restrict__ m1b,
    const float* __restrict__ m2w, const float* __restrict__ m2b,
    float* __restrict__ ws, float* __restrict__ out) {
  __shared__ float tok[NW][DD], kvb[NW][DD], vvb[NW][DD];
  __shared__ float hbuf[NW][NFFN];
  __shared__ float feat[2 * DD];
  __shared__ float red[2];
  __shared__ float4 wbuf4[4352];  // 68 KB padded staging buffer
  int tid = threadIdx.x;
  int tk = tid >> 6, d = tid & 63;
  int row = blockIdx.x, b = row / NNEG;
  tok[tk][d] = ws[OFF_TOK + row * NW * DD + tk * DD + d];
  for (int f = 0; f < NFL; ++f) {
    // ---- stage wq,wk,wv,wo as 4x [64][68] ----
    {
      const float4* s0 = (const float4*)(wq + (size_t)f * DD * DD);
      const float4* s1 = (const float4*)(wk + (size_t)f * DD * DD);
      const float4* s2 = (const float4*)(wv + (size_t)f * DD * DD);
      const float4* s3 = (const float4*)(wo + (size_t)f * DD * DD);
      for (int idx = tid; idx < 4096; idx += 192) {
        int m = idx >> 10, rem = idx & 1023;
        int rrow = rem >> 4, c4 = rem & 15;
        const float4* s = (m == 0) ? s0 : (m == 1) ? s1 : (m == 2) ? s2 : s3;
        wbuf4[(m * 64 + rrow) * 17 + c4] = s[rem];
      }
    }
    __syncthreads();
    // ---- QKV from LDS ----
    float qd = 0.f, kd = 0.f, vd = 0.f;
#pragma unroll
    for (int kk = 0; kk < 16; ++kk) {
      float4 tv = *(const float4*)&tok[tk][4 * kk];
      float4 aq = wbuf4[(0 * 64 + d) * 17 + kk];
      float4 ak = wbuf4[(1 * 64 + d) * 17 + kk];
      float4 av = wbuf4[(2 * 64 + d) * 17 + kk];
      qd += tv.x * aq.x + tv.y * aq.y + tv.z * aq.z + tv.w * aq.w;
      kd += tv.x * ak.x + tv.y * ak.y + tv.z * ak.z + tv.w * ak.w;
      vd += tv.x * av.x + tv.y * av.y + tv.z * av.z + tv.w * av.w;
    }
    kvb[tk][d] = kd;
    vvb[tk][d] = vd;
    __syncthreads();
    // ---- attention (head = d>>4) ----
    float sc[NW];
#pragma unroll
    for (int j = 0; j < NW; ++j) {
      float p = qd * kvb[j][d];
      p += __shfl_xor(p, 1);
      p += __shfl_xor(p, 2);
      p += __shfl_xor(p, 4);
      p += __shfl_xor(p, 8);
      sc[j] = p * 0.25f;  // 1/sqrt(16)
    }
    float mx = fmaxf(sc[0], fmaxf(sc[1], sc[2]));
    float e0 = expf(sc[0] - mx), e1 = expf(sc[1] - mx), e2 = expf(sc[2] - mx);
    float inv = 1.f / (e0 + e1 + e2);
    float od = (e0 * vvb[0][d] + e1 * vvb[1][d] + e2 * vvb[2][d]) * inv;
    __syncthreads();
    kvb[tk][d] = od;  // reuse as o-buffer (wave-private)
    // ---- o @ wo.T ----
    float ao = 0.f;
#pragma unroll
    for (int kk = 0; kk < 16; ++kk) {
      float4 ov = *(const float4*)&kvb[tk][4 * kk];
      float4 w4 = wbuf4[(3 * 64 + d) * 17 + kk];
      ao += ov.x * w4.x + ov.y * w4.y + ov.z * w4.z + ov.w * w4.w;
    }
    float t1 = tok[tk][d] + ao;
    // ---- LN1 ----
    float s = t1;
    for (int m = 1; m < 64; m <<= 1) s += __shfl_xor(s, m);
    float mean = s * (1.f / 64.f);
    float cv = t1 - mean;
    float v = cv * cv;
    for (int m = 1; m < 64; m <<= 1) v += __shfl_xor(v, m);
    v *= (1.f / 64.f);
    t1 = cv * __frsqrt_rn(v + LN_EPS) * fln1s[f * DD + d] + fln1b[f * DD + d];
    tok[tk][d] = t1;
    __syncthreads();
    // ---- stage ffw1 [256][68] ----
    {
      const float4* s4 = (const float4*)(ffw1 + (size_t)f * NFFN * DD);
      for (int idx = tid; idx < 4096; idx += 192) {
        int rrow = idx >> 4, c4 = idx & 15;
        wbuf4[rrow * 17 + c4] = s4[idx];
      }
    }
    __syncthreads();
    // ---- FFN1 ----
    float h[4];
#pragma unroll
    for (int uu = 0; uu < 4; ++uu) h[uu] = ffb1[f * NFFN + d + 64 * uu];
#pragma unroll
    for (int kk = 0; kk < 16; ++kk) {
      float4 tv = *(const float4*)&tok[tk][4 * kk];
      float4 w0 = wbuf4[(d + 0) * 17 + kk];
      float4 w1 = wbuf4[(d + 64) * 17 + kk];
      float4 w2 = wbuf4[(d + 128) * 17 + kk];
      float4 w3 = wbuf4[(d + 192) * 17 + kk];
      h[0] += tv.x * w0.x + tv.y * w0.y + tv.z * w0.z + tv.w * w0.w;
      h[1] += tv.x * w1.x + tv.y * w1.y + tv.z * w1.z + tv.w * w1.w;
      h[2] += tv.x * w2.x + tv.y * w2.y + tv.z * w2.z + tv.w * w2.w;
      h[3] += tv.x * w3.x + tv.y * w3.y + tv.z * w3.z + tv.w * w3.w;
    }
#pragma unroll
    for (int uu = 0; uu < 4; ++uu) hbuf[tk][d + 64 * uu] = fmaxf(h[uu], 0.f);
    __syncthreads();
    // ---- stage ffw2 [64][260] ----
    {
      const float4* s4 = (const float4*)(ffw2 + (size_t)f * DD * NFFN);
      for (int idx = tid; idx < 4096; idx += 192) {
        int rrow = idx >> 6, c4 = idx & 63;
        wbuf4[rrow * 65 + c4] = s4[idx];
      }
    }
    __syncthreads();
    // ---- FFN2 ----
    float ff = ffb2[f * DD + d];
#pragma unroll 8
    for (int kk = 0; kk < 64; ++kk) {
      float4 hv = *(const float4*)&hbuf[tk][4 * kk];
      float4 w4 = wbuf4[d * 65 + kk];
      ff += hv.x * w4.x + hv.y * w4.y + hv.z * w4.z + hv.w * w4.w;
    }
    float t2 = t1 + ff;
    // ---- LN2 ----
    s = t2;
    for (int m = 1; m < 64; m <<= 1) s += __shfl_xor(s, m);
    mean = s * (1.f / 64.f);
    cv = t2 - mean;
    v = cv * cv;
    for (int m = 1; m < 64; m <<= 1) v += __shfl_xor(v, m);
    v *= (1.f / 64.f);
    t2 = cv * __frsqrt_rn(v + LN_EPS) * fln2s[f * DD + d] + fln2b[f * DD + d];
    tok[tk][d] = t2;
    __syncthreads();
  }
  // ---- final MLP ----
  if (tk == 2) {
    feat[d] = tok[2][d];
    feat[DD + d] = ws[OFF_QUERY + b * DD + d];
  }
  {
    const float4* s4 = (const float4*)m1w;
    for (int idx = tid; idx < 4096; idx += 192) {
      int rrow = idx >> 5, c4 = idx & 31;
      wbuf4[rrow * 33 + c4] = s4[idx];
    }
  }
  __syncthreads();
  float partial = 0.f;
  if (tid < 2 * DD) {
    int hh = tid;
    float acc = m1b[hh];
#pragma unroll
    for (int kk = 0; kk < 32; ++kk) {
      float4 fv = *(const float4*)&feat[4 * kk];
      float4 w4 = wbuf4[hh * 33 + kk];
      acc += fv.x * w4.x + fv.y * w4.y + fv.z * w4.z + fv.w * w4.w;
    }
    acc = fmaxf(acc, 0.f);
    partial = acc * m2w[hh];
  }
  for (int m = 1; m < 64; m <<= 1) partial += __shfl_xor(partial, m);
  if (d == 0 && tk < 2) red[tk] = partial;
  __syncthreads();
  if (tid == 0) out[row] = red[0] + red[1] + m2b[0];
}

extern "C" void kernel_launch(void* const* d_in, const int* in_sizes, int n_in,
                              void* d_out, int out_size, void* d_ws, size_t ws_size,
                              hipStream_t stream) {
  const int* qt = (const int*)d_in[0];
  const int* eidx = (const int*)d_in[1];
  const int* etype = (const int*)d_in[2];
  const int* etime = (const int*)d_in[3];
  const float* qemb = (const float*)d_in[4];
  const float* ew = (const float*)d_in[5];
  const float* rlw = (const float*)d_in[6];
  const float* rlb = (const float*)d_in[7];
  const float* tw = (const float*)d_in[8];
  const float* tb = (const float*)d_in[9];
  const float* linw = (const float*)d_in[10];
  const float* linb = (const float*)d_in[11];
  const float* lns = (const float*)d_in[12];
  const float* lnb = (const float*)d_in[13];
  const float* pe = (const float*)d_in[14];
  const float* wq = (const float*)d_in[15];
  const float* wk = (const float*)d_in[16];
  const float* wv = (const float*)d_in[17];
  const float* wo = (const float*)d_in[18];
  const float* ffw1 = (const float*)d_in[19];
  const float* ffb1 = (const float*)d_in[20];
  const float* ffw2 = (const float*)d_in[21];
  const float* ffb2 = (const float*)d_in[22];
  const float* fln1s = (const float*)d_in[23];
  const float* fln1b = (const float*)d_in[24];
  const float* fln2s = (const float*)d_in[25];
  const float* fln2b = (const float*)d_in[26];
  const float* m1w = (const float*)d_in[27];
  const float* m1b = (const float*)d_in[28];
  const float* m2w = (const float*)d_in[29];
  const float* m2b = (const float*)d_in[30];
  float* ws = (float*)d_ws;
  float* out = (float*)d_out;

  k_prep<<<1, 256, 0, stream>>>(qt, qemb, ws);
  k_mint<<<(NE + 255) / 256, 256, 0, stream>>>(etime, ws);
  k_zero_ptr<<<(NW * (NN + 1) + 255) / 256, 256, 0, stream>>>(ws);
  k_twprep<<<(NL * NR * NB * DD + 255) / 256, 256, 0, stream>>>(tw, tb, ws);
  k_transpose<<<(NL * 2 * DD * DD + 255) / 256, 256, 0, stream>>>(linw, ws);
  k_rel<<<dim3(NR * DD / 256, NL), 256, 0, stream>>>(rlw, rlb, ws);
  k_hist<<<dim3((NE + 255) / 256, NW), 256, 0, stream>>>(eidx, ws);
  k_scan<<<NW, 256, 0, stream>>>(ws);
  k_curinit<<<(NW * NN + 255) / 256, 256, 0, stream>>>(ws);
  k_scatter<<<dim3((NE + 255) / 256, NW), 256, 0, stream>>>(eidx, etype, etime, ew, ws);

  float* X = ws + OFF_X;
  float* X2 = ws + OFF_X2;
  for (int w = 0; w < NW; ++w) {
    float* cur = X;
    float* nxt = X2;
    for (int l = 0; l < NL; ++l) {
      int init0 = (l == 0) ? 1 : 0;
      k_agg<<<NN / 4, 256, 0, stream>>>(cur, ws, w, l, init0);
      k_gemm<<<NB * NN / 32, 256, 0, stream>>>(linb, lns, lnb, cur, nxt, ws, l, init0);
      float* t = cur; cur = nxt; nxt = t;
    }
    k_gather<<<(NB * NNEG * DD + 255) / 256, 256, 0, stream>>>(pe, cur, ws, w);
  }
  k_xform<<<NB * NNEG, 192, 0, stream>>>(wq, wk, wv, wo, ffw1, ffb1, ffw2, ffb2, fln1s,
                                          fln1b, fln2s, fln2b, m1w, m1b, m2w, m2b, ws, out);
}